// Round 9
// baseline (4914.800 us; speedup 1.0000x reference)
//
#include <hip/hip_runtime.h>

// ---------------------------------------------------------------------------
// Fused recurrent multimodal net (3×LSTM + attention + gated memory + out MLP)
// T=128, N=2048. One block = 16 batch rows for all 128 steps. 128 blocks.
// Weights pre-packed to bf16 MFMA B-fragment tiles in d_ws (~1.26 MB).
// Round 8: register async pipeline. B-tiles stream via raw asm
// global_load_dwordx4 into an 8-deep VGPR ring with exact counted vmcnt
// (7..0 tail decay, no dummy loads), MFMA consumes registers directly
// (no LDS hop / no lgkmcnt chain of r7). A-fragments prefetched 1 iter
// ahead so ds_read latency hides under the vmcnt stall.
// ---------------------------------------------------------------------------

#define T_STEPS 128

typedef __attribute__((ext_vector_type(8))) short bf16x8;
typedef __attribute__((ext_vector_type(4))) float f32x4;

#define MFMA_B16(a,b,c) __builtin_amdgcn_mfma_f32_16x16x32_bf16((a),(b),(c),0,0,0)

__device__ __forceinline__ unsigned short f2b(float v) {
  union { float f; unsigned u; } x; x.f = v;
  unsigned r = x.u + 0x7fffu + ((x.u >> 16) & 1u);
  return (unsigned short)(r >> 16);
}
__device__ __forceinline__ float b2f(unsigned short u) {
  union { unsigned u; float f; } x; x.u = ((unsigned)u) << 16; return x.f;
}
__device__ __forceinline__ float sigm(float x){ return 1.0f/(1.0f + __expf(-x)); }
__device__ __forceinline__ float tanh_(float x){ return 1.0f - 2.0f/(1.0f + __expf(2.0f*x)); }

// ---- core LDS layout (bytes), 16 rows per buffer, strides padded ----------
#define OFF_XL     0        // 16 x 328 bf16 (x_lin, K padded to 320)
#define OFF_XA     10496    // 16 x 104 (x_ac, K->96)
#define OFF_XI     13824    // 16 x 72  (x_im, K->64)
#define OFF_CSTAR  16128    // 16 x 456 (c_star 448)
#define OFF_ATT    30720    // 16 x 456 (logits -> attended, in place)
#define OFF_HID    45312    // 16 x 264: att1h(136)/att2h(264)/outh(72)
#define OFF_G1H    53760    // 16 x 72
#define OFF_G2H    56064    // 16 x 72
#define OFF_FEATS  58368    // 16 x 360 ([h_l|h_a|h_i|mem])
#define OFF_BIAS   69888    // 2369 f32
// 82944 > 81920: force 1 block/CU (4 waves/SIMD) so arch-VGPR budget is max.
#define LDS_BYTES  82944

// ---- bias layout (f32 indices) ----
#define BG_LIN 0
#define BG_AC  384
#define BG_IM  576
#define B_A1H  960
#define B_LOG  1088
#define B_A2H  1536
#define B_CHAT 1792
#define B_G1H  1920
#define B_G2H  1984
#define B_GM1  2048
#define B_GM2  2176
#define B_OUTH 2304
#define B_OUT2 2368
#define N_BIAS 2369

// ---- pack tile region bases (tiles of 1KB) ----
#define N_TILES 1226
#define PACK_BYTES ((size_t)N_TILES * 1024)

#define LA(off,st,row,kk)  (*(const bf16x8*)(lds + (off) + ((((row)*(st)) + (kk)) << 1)))
#define LB(tile)           (*(const bf16x8*)(packc + (((size_t)(tile)) << 10) + (lane << 4)))
#define STB(off,st,row,col,v) (*(unsigned short*)(lds + (off) + ((((row)*(st)) + (col)) << 1)) = f2b(v))
#define LDB(off,st,row,col)   b2f(*(const unsigned short*)(lds + (off) + ((((row)*(st)) + (col)) << 1)))

struct PP { const float* p[35]; };

// ---------------------------------------------------------------------------
// Register async-pipeline primitives
// ---------------------------------------------------------------------------
__device__ __forceinline__ void vmw(int n) {
  switch (n) {
    case 0: asm volatile("s_waitcnt vmcnt(0)"); break;
    case 1: asm volatile("s_waitcnt vmcnt(1)"); break;
    case 2: asm volatile("s_waitcnt vmcnt(2)"); break;
    case 3: asm volatile("s_waitcnt vmcnt(3)"); break;
    case 4: asm volatile("s_waitcnt vmcnt(4)"); break;
    case 5: asm volatile("s_waitcnt vmcnt(5)"); break;
    case 6: asm volatile("s_waitcnt vmcnt(6)"); break;
    default: asm volatile("s_waitcnt vmcnt(7)"); break;
  }
  __builtin_amdgcn_sched_barrier(0);
}

#define ISSUE_B(dst, tile)                                                   \
  { unsigned off_ = (((unsigned)(tile)) << 10) + ((unsigned)lane << 4);      \
    asm volatile("global_load_dwordx4 %0, %1, %2"                            \
                 : "=v"(dst) : "v"(off_), "s"(packc)); }

// reg_loop: 8-deep VGPR ring. Iter i waits vmcnt(min(NTT-1-i,7)) -> tile i is
// resident in b[i&7]; body consumes it; then tile i+8 is issued into the slot.
// Tail: issues stop, wait count decays 7..0 (exact counting, no dummies).
template<int NTT, class FT, class FB>
__device__ __forceinline__ void reg_loop(const char* packc, int lane,
                                         FT&& tile_of, FB&& body)
{
  constexpr int D = (NTT < 8) ? NTT : 8;
  bf16x8 b[8];
  #pragma unroll
  for (int i = 0; i < D; ++i) ISSUE_B(b[i], tile_of(i));
  #pragma unroll
  for (int i = 0; i < NTT; ++i) {
    vmw((NTT-1-i) < 7 ? (NTT-1-i) : 7);
    body(i, b[i & 7]);
    __builtin_amdgcn_sched_barrier(0);
    if (i + 8 < NTT) ISSUE_B(b[i & 7], tile_of(i + 8));
  }
}

// ---------------------------------------------------------------------------
// Pack kernel (unchanged): fp32 weights -> bf16 B-fragment tiles + biases.
// ---------------------------------------------------------------------------
__device__ __forceinline__ float gate_src(const float* Wih, const float* Whh,
                                          int H, int din, int nksx, int col, int k)
{
  int blk = col >> 6, gate = (col >> 4) & 3, u = col & 15;
  int unit = blk*16 + u;
  if (unit >= H) return 0.f;
  int row = gate*H + unit;
  int xk = nksx*32;
  if (k < xk) return (k < din) ? Wih[row*din + k] : 0.f;
  int kk = k - xk;
  return (kk < H) ? Whh[row*H + kk] : 0.f;
}
__device__ __forceinline__ float plain_src(const float* W, int nout, int kdim, int col, int k)
{
  return (col < nout && k < kdim) ? W[col*kdim + k] : 0.f;
}

__global__ __launch_bounds__(256) void pack_kernel(PP P, unsigned short* __restrict__ pack,
                                                   float* __restrict__ bias)
{
  int tid = blockIdx.x*blockDim.x + threadIdx.x;
  int wv = tid >> 6, lane = tid & 63;
  int nw = (gridDim.x*blockDim.x) >> 6;
  int c = lane & 15, kg = lane >> 4;

  for (int tile = wv; tile < N_TILES; tile += nw) {
    unsigned short* dst = pack + ((size_t)tile << 9) + lane*8;
    #pragma unroll
    for (int i = 0; i < 8; ++i) {
      int r = tile; int nt, ks; float v; int kk;
      if (r < 312)       { nt=r/13; ks=r-nt*13; kk=ks*32+kg*8+i; v = gate_src(P.p[3], P.p[4], 88,300,10, nt*16+c, kk); }
      else if (r < 372)  { r-=312; nt=r/5;  ks=r-nt*5;  kk=ks*32+kg*8+i; v = gate_src(P.p[7], P.p[8], 48, 74, 3, nt*16+c, kk); }
      else if (r < 492)  { r-=372; nt=r/5;  ks=r-nt*5;  kk=ks*32+kg*8+i; v = gate_src(P.p[11],P.p[12],88, 35, 2, nt*16+c, kk); }
      else if (r < 604)  { r-=492; nt=r/14; ks=r-nt*14; kk=ks*32+kg*8+i; v = plain_src(P.p[15],128,448, nt*16+c, kk); }
      else if (r < 716)  { r-=604; nt=r/4;  ks=r-nt*4;  kk=ks*32+kg*8+i; v = plain_src(P.p[17],448,128, nt*16+c, kk); }
      else if (r < 940)  { r-=716; nt=r/14; ks=r-nt*14; kk=ks*32+kg*8+i; v = plain_src(P.p[19],256,448, nt*16+c, kk); }
      else if (r < 1004) { r-=940; nt=r/8;  ks=r-nt*8;  kk=ks*32+kg*8+i; v = plain_src(P.p[21],128,256, nt*16+c, kk); }
      else if (r < 1076) { r-=1004; nt=r/18; ks=r-nt*18; kk=ks*32+kg*8+i; v = plain_src(P.p[23], 64,576, nt*16+c, kk); }
      else if (r < 1148) { r-=1076; nt=r/18; ks=r-nt*18; kk=ks*32+kg*8+i; v = plain_src(P.p[27], 64,576, nt*16+c, kk); }
      else if (r < 1164) { r-=1148; nt=r/2;  ks=r-nt*2;  kk=ks*32+kg*8+i; v = plain_src(P.p[25],128, 64, nt*16+c, kk); }
      else if (r < 1180) { r-=1164; nt=r/2;  ks=r-nt*2;  kk=ks*32+kg*8+i; v = plain_src(P.p[29],128, 64, nt*16+c, kk); }
      else if (r < 1224) { r-=1180; nt=r/11; ks=r-nt*11; kk=ks*32+kg*8+i; v = plain_src(P.p[31], 64,352, nt*16+c, kk); }
      else               { r-=1224; nt=0;    ks=r;       kk=ks*32+kg*8+i; v = plain_src(P.p[33],  1, 64, nt*16+c, kk); }
      dst[i] = f2b(v);
    }
  }

  int NT = gridDim.x*blockDim.x;
  for (int b = tid; b < N_BIAS; b += NT) {
    float v; int r = b;
    if (r < 384)       { int blk=r>>6, g=(r>>4)&3, u=r&15, un=blk*16+u; v = (un<88) ? P.p[5][g*88+un] + P.p[6][g*88+un]  : 0.f; }
    else if (r < 576)  { r-=384; int blk=r>>6, g=(r>>4)&3, u=r&15, un=blk*16+u; v = (un<48) ? P.p[9][g*48+un] + P.p[10][g*48+un] : 0.f; }
    else if (r < 960)  { r-=576; int blk=r>>6, g=(r>>4)&3, u=r&15, un=blk*16+u; v = (un<88) ? P.p[13][g*88+un]+ P.p[14][g*88+un] : 0.f; }
    else if (r < 1088) v = P.p[16][r-960];
    else if (r < 1536) v = P.p[18][r-1088];
    else if (r < 1792) v = P.p[20][r-1536];
    else if (r < 1920) v = P.p[22][r-1792];
    else if (r < 1984) v = P.p[24][r-1920];
    else if (r < 2048) v = P.p[28][r-1984];
    else if (r < 2176) v = P.p[26][r-2048];
    else if (r < 2304) v = P.p[30][r-2176];
    else if (r < 2368) v = P.p[32][r-2304];
    else               v = P.p[34][0];
    bias[b] = v;
  }
}

// ---------------------------------------------------------------------------
// Main fused kernel
// ---------------------------------------------------------------------------
struct GT { int blk, tb, kt, nksx, nks, xoff, xst, hsec, bb, H; };
__device__ __forceinline__ GT gate_task(int tau) {
  GT g;
  if (tau < 6)       { g.blk=tau;   g.tb=0   + g.blk*4*13; g.kt=13; g.nksx=10; g.nks=13; g.xoff=OFF_XL; g.xst=328; g.hsec=0;   g.bb=BG_LIN; g.H=88; }
  else if (tau < 9)  { g.blk=tau-6; g.tb=312 + g.blk*4*5;  g.kt=5;  g.nksx=3;  g.nks=5;  g.xoff=OFF_XA; g.xst=104; g.hsec=88;  g.bb=BG_AC;  g.H=48; }
  else               { g.blk=tau-9; g.tb=372 + g.blk*4*5;  g.kt=5;  g.nksx=2;  g.nks=5;  g.xoff=OFF_XI; g.xst=72;  g.hsec=136; g.bb=BG_IM;  g.H=88; }
  return g;
}

template<int NKSX,int NKS>
__device__ __forceinline__ void gate_reg(f32x4 acc[4], const char* lds, const char* packc,
    int lane, int rA, int gA, int xoff, int xst, int hsec, int tb, int kt)
{
  bf16x8 a = LA(xoff, xst, rA, gA*8);        // s = 0
  reg_loop<NKS*4>(packc, lane,
    [&](int i){ return tb + (i & 3)*kt + (i >> 2); },
    [&](int i, bf16x8 bv){
      int q = i & 3, s = i >> 2;
      acc[q] = MFMA_B16(a, bv, acc[q]);
      if (q == 3 && s + 1 < NKS) {
        int s2 = s + 1;
        a = (s2 < NKSX) ? LA(xoff, xst, rA, s2*32 + gA*8)
                        : LA(OFF_FEATS, 360, rA, hsec + (s2-NKSX)*32 + gA*8);
      }
    });
}

__device__ __forceinline__ void stage_x(char* lds, const float* __restrict__ xlin,
    const float* __restrict__ xac, const float* __restrict__ xim, int t, int n0,
    int tid0, int nthr)
{
  const size_t tb = (size_t)t*2048 + n0;
  for (int q = tid0; q < 1200; q += nthr) {          // lin: 16 rows x 75 float4
    int row = q/75, d = q - row*75;
    float4 v = *(const float4*)(xlin + (tb+row)*300 + d*4);
    unsigned long long u = (unsigned long long)f2b(v.x)
      | ((unsigned long long)f2b(v.y) << 16)
      | ((unsigned long long)f2b(v.z) << 32)
      | ((unsigned long long)f2b(v.w) << 48);
    *(unsigned long long*)(lds + OFF_XL + (((size_t)row*328 + d*4) << 1)) = u;
  }
  for (int q = tid0; q < 592; q += nthr) {           // ac: 16 x 37 float2
    int row = q/37, d = q - row*37;
    float2 v = *(const float2*)(xac + (tb+row)*74 + d*2);
    unsigned uu = (unsigned)f2b(v.x) | ((unsigned)f2b(v.y) << 16);
    *(unsigned*)(lds + OFF_XA + (((size_t)row*104 + d*2) << 1)) = uu;
  }
  for (int q = tid0; q < 560; q += nthr) {           // im: 16 x 35 scalar
    int row = q/35, d = q - row*35;
    *(unsigned short*)(lds + OFF_XI + (((size_t)row*72 + d) << 1)) = f2b(xim[(tb+row)*35 + d]);
  }
}

__global__ __launch_bounds__(1024) void fused_kernel(
    const float* __restrict__ xlin, const float* __restrict__ xac, const float* __restrict__ xim,
    const unsigned short* __restrict__ pack, const float* __restrict__ biasg,
    float* __restrict__ out)
{
  __shared__ alignas(16) char lds[LDS_BYTES];
  const char* packc = (const char*)pack;
  const int tid  = threadIdx.x;
  const int lane = tid & 63;
  const int w    = tid >> 6;           // wave 0..15
  const int rA   = lane & 15;          // A row / C col
  const int gA   = lane >> 4;          // k-group / C row-group
  const int n0   = blockIdx.x * 16;
  float* biasLds = (float*)(lds + OFF_BIAS);

  for (int i = tid; i < (OFF_BIAS >> 2); i += 1024) ((int*)lds)[i] = 0;
  __syncthreads();
  for (int i = tid; i < N_BIAS; i += 1024) biasLds[i] = biasg[i];
  stage_x(lds, xlin, xac, xim, 0, n0, tid, 1024);
  __syncthreads();

  float cst[4]  = {};   // LSTM cell state (per-lane, fp32, persistent)
  float mreg[4] = {};   // memory state (waves 0..7, fp32, persistent)

  for (int t = 0; t < T_STEPS; ++t) {
    // ---- Phase 1: gate matmuls (waves 0..14); wave 15: out2 of step t-1 ----
    f32x4 gacc[4];
    if (w == 15) {
      if (t > 0) {
        float bv = biasLds[B_OUT2];
        f32x4 oa0 = {bv,bv,bv,bv};
        bf16x8 as[2], bs[2];
        #pragma unroll
        for (int s = 0; s < 2; ++s) { bs[s] = LB(1224 + s); as[s] = LA(OFF_HID,72, rA, s*32+gA*8); }
        #pragma unroll
        for (int s = 0; s < 2; ++s) oa0 = MFMA_B16(as[s], bs[s], oa0);
        if (rA == 0) {
          #pragma unroll
          for (int j = 0; j < 4; ++j)
            __builtin_nontemporal_store(oa0[j], &out[(size_t)(n0 + gA*4 + j)*T_STEPS + (t-1)]);
        }
      }
    } else {
      GT g = gate_task(w);
      #pragma unroll
      for (int q = 0; q < 4; ++q) {
        float bv = biasLds[g.bb + g.blk*64 + q*16 + rA];
        gacc[q] = (f32x4){bv,bv,bv,bv};
      }
      if (w < 6)      gate_reg<10,13>(gacc, lds, packc, lane, rA, gA, g.xoff, g.xst, g.hsec, g.tb, g.kt);
      else if (w < 9) gate_reg<3,5>  (gacc, lds, packc, lane, rA, gA, g.xoff, g.xst, g.hsec, g.tb, g.kt);
      else            gate_reg<2,5>  (gacc, lds, packc, lane, rA, gA, g.xoff, g.xst, g.hsec, g.tb, g.kt);
    }
    __syncthreads();

    // ---- Phase 2: LSTM elementwise; write c_star(prev,new) + feats(h) ----
    if (w < 15) {
      GT g = gate_task(w);
      int unit = g.blk*16 + rA;
      if (unit < g.H) {
        #pragma unroll
        for (int j = 0; j < 4; ++j) {
          float iv = sigm (gacc[0][j]);
          float fv = sigm (gacc[1][j]);
          float gv = tanh_(gacc[2][j]);
          float ov = sigm (gacc[3][j]);
          float cp = cst[j];
          float cn = fv*cp + iv*gv;
          float hn = ov*tanh_(cn);
          cst[j] = cn;
          int row = gA*4 + j;
          STB(OFF_CSTAR,456, row, g.hsec + unit,        cp);
          STB(OFF_CSTAR,456, row, 224 + g.hsec + unit,  cn);
          STB(OFF_FEATS,360, row, g.hsec + unit,        hn);
        }
      }
    }
    __syncthreads();

    // ---- Phase 3: att1 layer1 (c_star -> relu -> att1h) ----
    if (w < 8) {
      int n = w;
      float bv = biasLds[B_A1H + n*16 + rA];
      f32x4 a0v = {bv,bv,bv,bv};
      bf16x8 a = LA(OFF_CSTAR,456, rA, gA*8);
      reg_loop<14>(packc, lane,
        [&](int i){ return 492 + n*14 + i; },
        [&](int i, bf16x8 bv8){
          a0v = MFMA_B16(a, bv8, a0v);
          if (i + 1 < 14) a = LA(OFF_CSTAR,456, rA, (i+1)*32+gA*8);
        });
      #pragma unroll
      for (int j = 0; j < 4; ++j)
        STB(OFF_HID,136, gA*4 + j, n*16 + rA, fmaxf(a0v[j], 0.f));
    }
    __syncthreads();

    // ---- Phase 4: att1 layer2 -> logits (att_buf) ----
    {
      float bv1 = biasLds[B_LOG + w*16 + rA];
      if (w < 12) {
        float bv2 = biasLds[B_LOG + (w+16)*16 + rA];
        f32x4 l0 = {bv1,bv1,bv1,bv1}, l1 = {bv2,bv2,bv2,bv2};
        bf16x8 a = LA(OFF_HID,136, rA, gA*8);
        reg_loop<8>(packc, lane,
          [&](int i){ int tau = (i < 4) ? w : (w + 16); return 604 + tau*4 + (i & 3); },
          [&](int i, bf16x8 bv8){
            if (i < 4) l0 = MFMA_B16(a, bv8, l0); else l1 = MFMA_B16(a, bv8, l1);
            if (i + 1 < 8) a = LA(OFF_HID,136, rA, ((i+1)&3)*32+gA*8);
          });
        #pragma unroll
        for (int j = 0; j < 4; ++j) {
          STB(OFF_ATT,456, gA*4 + j, w*16 + rA,      l0[j]);
          STB(OFF_ATT,456, gA*4 + j, (w+16)*16 + rA, l1[j]);
        }
      } else {
        f32x4 l0 = {bv1,bv1,bv1,bv1};
        bf16x8 a = LA(OFF_HID,136, rA, gA*8);
        reg_loop<4>(packc, lane,
          [&](int i){ return 604 + w*4 + i; },
          [&](int i, bf16x8 bv8){
            l0 = MFMA_B16(a, bv8, l0);
            if (i + 1 < 4) a = LA(OFF_HID,136, rA, (i+1)*32+gA*8);
          });
        #pragma unroll
        for (int j = 0; j < 4; ++j)
          STB(OFF_ATT,456, gA*4 + j, w*16 + rA, l0[j]);
      }
    }
    __syncthreads();

    // ---- Phase 5: softmax(448)*c_star (waves 0..7) ; stage x_{t+1} (8..15) --
    if (w < 8) {
      int row = w*2 + (lane >> 5);
      int cb  = lane & 31;
      float v[14];
      float mx = -3.0e38f;
      #pragma unroll
      for (int q = 0; q < 14; ++q) { v[q] = LDB(OFF_ATT,456,row, cb + 32*q); mx = fmaxf(mx, v[q]); }
      #pragma unroll
      for (int mk = 1; mk < 32; mk <<= 1) mx = fmaxf(mx, __shfl_xor(mx, mk));
      float sm = 0.f;
      #pragma unroll
      for (int q = 0; q < 14; ++q) { v[q] = __expf(v[q] - mx); sm += v[q]; }
      #pragma unroll
      for (int mk = 1; mk < 32; mk <<= 1) sm += __shfl_xor(sm, mk);
      float inv = 1.0f / sm;
      #pragma unroll
      for (int q = 0; q < 14; ++q) {
        int c = cb + 32*q;
        float cs = LDB(OFF_CSTAR,456,row,c);
        STB(OFF_ATT,456,row,c, v[q]*inv*cs);
      }
    } else if (t < T_STEPS-1) {
      stage_x(lds, xlin, xac, xim, t+1, n0, tid - 512, 512);
    }
    __syncthreads();

    // ---- Phase 6: att2 layer1 (waves 8..15, 2 n-tiles); g1/g2 (waves 0..7) --
    if (w >= 8) {
      int nb = (w - 8)*2;
      float b0 = biasLds[B_A2H + nb*16 + rA];
      float b1 = biasLds[B_A2H + (nb+1)*16 + rA];
      f32x4 A0 = {b0,b0,b0,b0}, A1 = {b1,b1,b1,b1};
      bf16x8 a = LA(OFF_ATT,456, rA, gA*8);
      reg_loop<28>(packc, lane,
        [&](int i){ int rr = (i >= 14) ? 1 : 0; int s = i - (rr ? 14 : 0); return 716 + (nb+rr)*14 + s; },
        [&](int i, bf16x8 bv8){
          if (i < 14) A0 = MFMA_B16(a, bv8, A0); else A1 = MFMA_B16(a, bv8, A1);
          if (i + 1 < 28) {
            int ns = (i + 1 < 14) ? (i + 1) : (i + 1 - 14);
            a = LA(OFF_ATT,456, rA, ns*32+gA*8);
          }
        });
      #pragma unroll
      for (int j = 0; j < 4; ++j) {
        STB(OFF_HID,264, gA*4 + j, nb*16 + rA,     fmaxf(A0[j], 0.f));
        STB(OFF_HID,264, gA*4 + j, (nb+1)*16 + rA, fmaxf(A1[j], 0.f));
      }
    } else {
      int which = w >> 2;          // 0: g1, 1: g2
      int n = w & 3;
      int tbq = which ? 1076 : 1004;
      int bb  = which ? B_G2H : B_G1H;
      int oo  = which ? OFF_G2H : OFF_G1H;
      float bv = biasLds[bb + n*16 + rA];
      f32x4 A0 = {bv,bv,bv,bv};
      bf16x8 a = LA(OFF_ATT,456, rA, gA*8);
      reg_loop<18>(packc, lane,
        [&](int i){ return tbq + n*18 + i; },
        [&](int i, bf16x8 bv8){
          A0 = MFMA_B16(a, bv8, A0);
          if (i + 1 < 18) {
            a = (i + 1 < 14) ? LA(OFF_ATT,456, rA, (i+1)*32+gA*8)
                             : LA(OFF_FEATS,360, rA, 224 + (i+1-14)*32 + gA*8);
          }
        });
      #pragma unroll
      for (int j = 0; j < 4; ++j)
        STB(oo,72, gA*4 + j, n*16 + rA, fmaxf(A0[j], 0.f));
    }
    __syncthreads();

    // ---- Phase 7: att2 layer2 (tanh->c_hat) + gammas + mem update ----
    if (w < 8) {
      int n = w;
      float bc = biasLds[B_CHAT + n*16 + rA];
      float b1 = biasLds[B_GM1  + n*16 + rA];
      float b2 = biasLds[B_GM2  + n*16 + rA];
      f32x4 cc0={bc,bc,bc,bc};
      f32x4 g10={b1,b1,b1,b1};
      f32x4 g20={b2,b2,b2,b2};
      bf16x8 a = LA(OFF_HID,264, rA, gA*8);
      reg_loop<12>(packc, lane,
        [&](int i){
          if (i < 8)  return 940 + n*8 + i;
          if (i < 10) return 1148 + n*2 + (i - 8);
          return 1164 + n*2 + (i - 10);
        },
        [&](int i, bf16x8 bv8){
          if (i < 8)       cc0 = MFMA_B16(a, bv8, cc0);
          else if (i < 10) g10 = MFMA_B16(a, bv8, g10);
          else             g20 = MFMA_B16(a, bv8, g20);
          if (i + 1 < 8)        a = LA(OFF_HID,264, rA, (i+1)*32+gA*8);
          else if (i + 1 < 10)  a = LA(OFF_G1H,72, rA, (i+1-8)*32+gA*8);
          else if (i + 1 < 12)  a = LA(OFF_G2H,72, rA, (i+1-10)*32+gA*8);
        });
      #pragma unroll
      for (int j = 0; j < 4; ++j) {
        float ch = tanh_(cc0[j]), ga = sigm(g10[j]), gb = sigm(g20[j]);
        float mn = ga*mreg[j] + gb*ch;
        mreg[j] = mn;
        STB(OFF_FEATS,360, gA*4 + j, 224 + n*16 + rA, mn);
      }
    }
    __syncthreads();

    // ---- Phase 8: out layer1 (feats -> relu -> outh) ----
    if (w < 4) {
      int n = w;
      float bv = biasLds[B_OUTH + n*16 + rA];
      f32x4 a0v = {bv,bv,bv,bv};
      bf16x8 a = LA(OFF_FEATS,360, rA, gA*8);
      reg_loop<11>(packc, lane,
        [&](int i){ return 1180 + n*11 + i; },
        [&](int i, bf16x8 bv8){
          a0v = MFMA_B16(a, bv8, a0v);
          if (i + 1 < 11) a = LA(OFF_FEATS,360, rA, (i+1)*32+gA*8);
        });
      #pragma unroll
      for (int j = 0; j < 4; ++j)
        STB(OFF_HID,72, gA*4 + j, n*16 + rA, fmaxf(a0v[j], 0.f));
    }
    __syncthreads();
  }

  // ---- Final out2 for t = 127 ----
  if (w == 15) {
    float bv = biasLds[B_OUT2];
    f32x4 oa0 = {bv,bv,bv,bv};
    bf16x8 as[2], bs[2];
    #pragma unroll
    for (int s = 0; s < 2; ++s) { bs[s] = LB(1224 + s); as[s] = LA(OFF_HID,72, rA, s*32+gA*8); }
    #pragma unroll
    for (int s = 0; s < 2; ++s) oa0 = MFMA_B16(as[s], bs[s], oa0);
    if (rA == 0) {
      #pragma unroll
      for (int j = 0; j < 4; ++j)
        __builtin_nontemporal_store(oa0[j], &out[(size_t)(n0 + gA*4 + j)*T_STEPS + 127]);
    }
  }
}

extern "C" void kernel_launch(void* const* d_in, const int* in_sizes, int n_in,
                              void* d_out, int out_size, void* d_ws, size_t ws_size,
                              hipStream_t stream) {
  (void)in_sizes; (void)n_in; (void)out_size; (void)ws_size;
  PP P;
  for (int i = 0; i < 35; ++i) P.p[i] = (const float*)d_in[i];
  unsigned short* pack = (unsigned short*)d_ws;
  float* bias = (float*)((char*)d_ws + PACK_BYTES);

  hipLaunchKernelGGL(pack_kernel, dim3(320), dim3(256), 0, stream, P, pack, bias);
  hipLaunchKernelGGL(fused_kernel, dim3(128), dim3(1024), 0, stream,
                     P.p[0], P.p[1], P.p[2], pack, bias, (float*)d_out);
}

// Round 10
// 4906.058 us; speedup vs baseline: 1.0018x; 1.0018x over previous
//
#include <hip/hip_runtime.h>

// ---------------------------------------------------------------------------
// Fused recurrent multimodal net (3×LSTM + attention + gated memory + out MLP)
// T=128, N=2048. One block = 16 batch rows for all 128 steps. 128 blocks.
// Weights pre-packed to bf16 MFMA B-fragment tiles in d_ws (~1.26 MB).
// Round 8: register async pipeline. B-tiles stream via raw asm
// global_load_dwordx4 into an 8-deep VGPR ring with exact counted vmcnt
// (7..0 tail decay, no dummy loads), MFMA consumes registers directly
// (no LDS hop / no lgkmcnt chain of r7). A-fragments prefetched 1 iter
// ahead so ds_read latency hides under the vmcnt stall.
// ---------------------------------------------------------------------------

#define T_STEPS 128

typedef __attribute__((ext_vector_type(8))) short bf16x8;
typedef __attribute__((ext_vector_type(4))) float f32x4;

#define MFMA_B16(a,b,c) __builtin_amdgcn_mfma_f32_16x16x32_bf16((a),(b),(c),0,0,0)

__device__ __forceinline__ unsigned short f2b(float v) {
  union { float f; unsigned u; } x; x.f = v;
  unsigned r = x.u + 0x7fffu + ((x.u >> 16) & 1u);
  return (unsigned short)(r >> 16);
}
__device__ __forceinline__ float b2f(unsigned short u) {
  union { unsigned u; float f; } x; x.u = ((unsigned)u) << 16; return x.f;
}
__device__ __forceinline__ float sigm(float x){ return 1.0f/(1.0f + __expf(-x)); }
__device__ __forceinline__ float tanh_(float x){ return 1.0f - 2.0f/(1.0f + __expf(2.0f*x)); }

// ---- core LDS layout (bytes), 16 rows per buffer, strides padded ----------
#define OFF_XL     0        // 16 x 328 bf16 (x_lin, K padded to 320)
#define OFF_XA     10496    // 16 x 104 (x_ac, K->96)
#define OFF_XI     13824    // 16 x 72  (x_im, K->64)
#define OFF_CSTAR  16128    // 16 x 456 (c_star 448)
#define OFF_ATT    30720    // 16 x 456 (logits -> attended, in place)
#define OFF_HID    45312    // 16 x 264: att1h(136)/att2h(264)/outh(72)
#define OFF_G1H    53760    // 16 x 72
#define OFF_G2H    56064    // 16 x 72
#define OFF_FEATS  58368    // 16 x 360 ([h_l|h_a|h_i|mem])
#define OFF_BIAS   69888    // 2369 f32
// 82944 > 81920: force 1 block/CU (4 waves/SIMD) so arch-VGPR budget is max.
#define LDS_BYTES  82944

// ---- bias layout (f32 indices) ----
#define BG_LIN 0
#define BG_AC  384
#define BG_IM  576
#define B_A1H  960
#define B_LOG  1088
#define B_A2H  1536
#define B_CHAT 1792
#define B_G1H  1920
#define B_G2H  1984
#define B_GM1  2048
#define B_GM2  2176
#define B_OUTH 2304
#define B_OUT2 2368
#define N_BIAS 2369

// ---- pack tile region bases (tiles of 1KB) ----
#define N_TILES 1226
#define PACK_BYTES ((size_t)N_TILES * 1024)

#define LA(off,st,row,kk)  (*(const bf16x8*)(lds + (off) + ((((row)*(st)) + (kk)) << 1)))
#define LB(tile)           (*(const bf16x8*)(packc + (((size_t)(tile)) << 10) + (lane << 4)))
#define STB(off,st,row,col,v) (*(unsigned short*)(lds + (off) + ((((row)*(st)) + (col)) << 1)) = f2b(v))
#define LDB(off,st,row,col)   b2f(*(const unsigned short*)(lds + (off) + ((((row)*(st)) + (col)) << 1)))

struct PP { const float* p[35]; };

// ---------------------------------------------------------------------------
// Register async-pipeline primitives
// ---------------------------------------------------------------------------
__device__ __forceinline__ void vmw(int n) {
  switch (n) {
    case 0: asm volatile("s_waitcnt vmcnt(0)"); break;
    case 1: asm volatile("s_waitcnt vmcnt(1)"); break;
    case 2: asm volatile("s_waitcnt vmcnt(2)"); break;
    case 3: asm volatile("s_waitcnt vmcnt(3)"); break;
    case 4: asm volatile("s_waitcnt vmcnt(4)"); break;
    case 5: asm volatile("s_waitcnt vmcnt(5)"); break;
    case 6: asm volatile("s_waitcnt vmcnt(6)"); break;
    default: asm volatile("s_waitcnt vmcnt(7)"); break;
  }
  __builtin_amdgcn_sched_barrier(0);
}

#define ISSUE_B(dst, tile)                                                   \
  { unsigned off_ = (((unsigned)(tile)) << 10) + ((unsigned)lane << 4);      \
    asm volatile("global_load_dwordx4 %0, %1, %2"                            \
                 : "=v"(dst) : "v"(off_), "s"(packc)); }

// reg_loop: 8-deep VGPR ring. Iter i waits vmcnt(min(NTT-1-i,7)) -> tile i is
// resident in b[i&7]; body consumes it; then tile i+8 is issued into the slot.
// Tail: issues stop, wait count decays 7..0 (exact counting, no dummies).
template<int NTT, class FT, class FB>
__device__ __forceinline__ void reg_loop(const char* packc, int lane,
                                         FT&& tile_of, FB&& body)
{
  constexpr int D = (NTT < 8) ? NTT : 8;
  bf16x8 b[8];
  #pragma unroll
  for (int i = 0; i < D; ++i) ISSUE_B(b[i], tile_of(i));
  #pragma unroll
  for (int i = 0; i < NTT; ++i) {
    vmw((NTT-1-i) < 7 ? (NTT-1-i) : 7);
    body(i, b[i & 7]);
    __builtin_amdgcn_sched_barrier(0);
    if (i + 8 < NTT) ISSUE_B(b[i & 7], tile_of(i + 8));
  }
}

// ---------------------------------------------------------------------------
// Pack kernel (unchanged): fp32 weights -> bf16 B-fragment tiles + biases.
// ---------------------------------------------------------------------------
__device__ __forceinline__ float gate_src(const float* Wih, const float* Whh,
                                          int H, int din, int nksx, int col, int k)
{
  int blk = col >> 6, gate = (col >> 4) & 3, u = col & 15;
  int unit = blk*16 + u;
  if (unit >= H) return 0.f;
  int row = gate*H + unit;
  int xk = nksx*32;
  if (k < xk) return (k < din) ? Wih[row*din + k] : 0.f;
  int kk = k - xk;
  return (kk < H) ? Whh[row*H + kk] : 0.f;
}
__device__ __forceinline__ float plain_src(const float* W, int nout, int kdim, int col, int k)
{
  return (col < nout && k < kdim) ? W[col*kdim + k] : 0.f;
}

__global__ __launch_bounds__(256) void pack_kernel(PP P, unsigned short* __restrict__ pack,
                                                   float* __restrict__ bias)
{
  int tid = blockIdx.x*blockDim.x + threadIdx.x;
  int wv = tid >> 6, lane = tid & 63;
  int nw = (gridDim.x*blockDim.x) >> 6;
  int c = lane & 15, kg = lane >> 4;

  for (int tile = wv; tile < N_TILES; tile += nw) {
    unsigned short* dst = pack + ((size_t)tile << 9) + lane*8;
    #pragma unroll
    for (int i = 0; i < 8; ++i) {
      int r = tile; int nt, ks; float v; int kk;
      if (r < 312)       { nt=r/13; ks=r-nt*13; kk=ks*32+kg*8+i; v = gate_src(P.p[3], P.p[4], 88,300,10, nt*16+c, kk); }
      else if (r < 372)  { r-=312; nt=r/5;  ks=r-nt*5;  kk=ks*32+kg*8+i; v = gate_src(P.p[7], P.p[8], 48, 74, 3, nt*16+c, kk); }
      else if (r < 492)  { r-=372; nt=r/5;  ks=r-nt*5;  kk=ks*32+kg*8+i; v = gate_src(P.p[11],P.p[12],88, 35, 2, nt*16+c, kk); }
      else if (r < 604)  { r-=492; nt=r/14; ks=r-nt*14; kk=ks*32+kg*8+i; v = plain_src(P.p[15],128,448, nt*16+c, kk); }
      else if (r < 716)  { r-=604; nt=r/4;  ks=r-nt*4;  kk=ks*32+kg*8+i; v = plain_src(P.p[17],448,128, nt*16+c, kk); }
      else if (r < 940)  { r-=716; nt=r/14; ks=r-nt*14; kk=ks*32+kg*8+i; v = plain_src(P.p[19],256,448, nt*16+c, kk); }
      else if (r < 1004) { r-=940; nt=r/8;  ks=r-nt*8;  kk=ks*32+kg*8+i; v = plain_src(P.p[21],128,256, nt*16+c, kk); }
      else if (r < 1076) { r-=1004; nt=r/18; ks=r-nt*18; kk=ks*32+kg*8+i; v = plain_src(P.p[23], 64,576, nt*16+c, kk); }
      else if (r < 1148) { r-=1076; nt=r/18; ks=r-nt*18; kk=ks*32+kg*8+i; v = plain_src(P.p[27], 64,576, nt*16+c, kk); }
      else if (r < 1164) { r-=1148; nt=r/2;  ks=r-nt*2;  kk=ks*32+kg*8+i; v = plain_src(P.p[25],128, 64, nt*16+c, kk); }
      else if (r < 1180) { r-=1164; nt=r/2;  ks=r-nt*2;  kk=ks*32+kg*8+i; v = plain_src(P.p[29],128, 64, nt*16+c, kk); }
      else if (r < 1224) { r-=1180; nt=r/11; ks=r-nt*11; kk=ks*32+kg*8+i; v = plain_src(P.p[31], 64,352, nt*16+c, kk); }
      else               { r-=1224; nt=0;    ks=r;       kk=ks*32+kg*8+i; v = plain_src(P.p[33],  1, 64, nt*16+c, kk); }
      dst[i] = f2b(v);
    }
  }

  int NT = gridDim.x*blockDim.x;
  for (int b = tid; b < N_BIAS; b += NT) {
    float v; int r = b;
    if (r < 384)       { int blk=r>>6, g=(r>>4)&3, u=r&15, un=blk*16+u; v = (un<88) ? P.p[5][g*88+un] + P.p[6][g*88+un]  : 0.f; }
    else if (r < 576)  { r-=384; int blk=r>>6, g=(r>>4)&3, u=r&15, un=blk*16+u; v = (un<48) ? P.p[9][g*48+un] + P.p[10][g*48+un] : 0.f; }
    else if (r < 960)  { r-=576; int blk=r>>6, g=(r>>4)&3, u=r&15, un=blk*16+u; v = (un<88) ? P.p[13][g*88+un]+ P.p[14][g*88+un] : 0.f; }
    else if (r < 1088) v = P.p[16][r-960];
    else if (r < 1536) v = P.p[18][r-1088];
    else if (r < 1792) v = P.p[20][r-1536];
    else if (r < 1920) v = P.p[22][r-1792];
    else if (r < 1984) v = P.p[24][r-1920];
    else if (r < 2048) v = P.p[28][r-1984];
    else if (r < 2176) v = P.p[26][r-2048];
    else if (r < 2304) v = P.p[30][r-2176];
    else if (r < 2368) v = P.p[32][r-2304];
    else               v = P.p[34][0];
    bias[b] = v;
  }
}

// ---------------------------------------------------------------------------
// Main fused kernel
// ---------------------------------------------------------------------------
struct GT { int blk, tb, kt, nksx, nks, xoff, xst, hsec, bb, H; };
__device__ __forceinline__ GT gate_task(int tau) {
  GT g;
  if (tau < 6)       { g.blk=tau;   g.tb=0   + g.blk*4*13; g.kt=13; g.nksx=10; g.nks=13; g.xoff=OFF_XL; g.xst=328; g.hsec=0;   g.bb=BG_LIN; g.H=88; }
  else if (tau < 9)  { g.blk=tau-6; g.tb=312 + g.blk*4*5;  g.kt=5;  g.nksx=3;  g.nks=5;  g.xoff=OFF_XA; g.xst=104; g.hsec=88;  g.bb=BG_AC;  g.H=48; }
  else               { g.blk=tau-9; g.tb=372 + g.blk*4*5;  g.kt=5;  g.nksx=2;  g.nks=5;  g.xoff=OFF_XI; g.xst=72;  g.hsec=136; g.bb=BG_IM;  g.H=88; }
  return g;
}

template<int NKSX,int NKS>
__device__ __forceinline__ void gate_reg(f32x4 acc[4], const char* lds, const char* packc,
    int lane, int rA, int gA, int xoff, int xst, int hsec, int tb, int kt)
{
  bf16x8 a = LA(xoff, xst, rA, gA*8);        // s = 0
  reg_loop<NKS*4>(packc, lane,
    [&](int i){ return tb + (i & 3)*kt + (i >> 2); },
    [&](int i, bf16x8 bv){
      int q = i & 3, s = i >> 2;
      acc[q] = MFMA_B16(a, bv, acc[q]);
      if (q == 3 && s + 1 < NKS) {
        int s2 = s + 1;
        a = (s2 < NKSX) ? LA(xoff, xst, rA, s2*32 + gA*8)
                        : LA(OFF_FEATS, 360, rA, hsec + (s2-NKSX)*32 + gA*8);
      }
    });
}

__device__ __forceinline__ void stage_x(char* lds, const float* __restrict__ xlin,
    const float* __restrict__ xac, const float* __restrict__ xim, int t, int n0,
    int tid0, int nthr)
{
  const size_t tb = (size_t)t*2048 + n0;
  for (int q = tid0; q < 1200; q += nthr) {          // lin: 16 rows x 75 float4
    int row = q/75, d = q - row*75;
    float4 v = *(const float4*)(xlin + (tb+row)*300 + d*4);
    unsigned long long u = (unsigned long long)f2b(v.x)
      | ((unsigned long long)f2b(v.y) << 16)
      | ((unsigned long long)f2b(v.z) << 32)
      | ((unsigned long long)f2b(v.w) << 48);
    *(unsigned long long*)(lds + OFF_XL + (((size_t)row*328 + d*4) << 1)) = u;
  }
  for (int q = tid0; q < 592; q += nthr) {           // ac: 16 x 37 float2
    int row = q/37, d = q - row*37;
    float2 v = *(const float2*)(xac + (tb+row)*74 + d*2);
    unsigned uu = (unsigned)f2b(v.x) | ((unsigned)f2b(v.y) << 16);
    *(unsigned*)(lds + OFF_XA + (((size_t)row*104 + d*2) << 1)) = uu;
  }
  for (int q = tid0; q < 560; q += nthr) {           // im: 16 x 35 scalar
    int row = q/35, d = q - row*35;
    *(unsigned short*)(lds + OFF_XI + (((size_t)row*72 + d) << 1)) = f2b(xim[(tb+row)*35 + d]);
  }
}

__global__ __launch_bounds__(1024) void fused_kernel(
    const float* __restrict__ xlin, const float* __restrict__ xac, const float* __restrict__ xim,
    const unsigned short* __restrict__ pack, const float* __restrict__ biasg,
    float* __restrict__ out)
{
  __shared__ alignas(16) char lds[LDS_BYTES];
  const char* packc = (const char*)pack;
  const int tid  = threadIdx.x;
  const int lane = tid & 63;
  const int w    = tid >> 6;           // wave 0..15
  const int rA   = lane & 15;          // A row / C col
  const int gA   = lane >> 4;          // k-group / C row-group
  const int n0   = blockIdx.x * 16;
  float* biasLds = (float*)(lds + OFF_BIAS);

  for (int i = tid; i < (OFF_BIAS >> 2); i += 1024) ((int*)lds)[i] = 0;
  __syncthreads();
  for (int i = tid; i < N_BIAS; i += 1024) biasLds[i] = biasg[i];
  stage_x(lds, xlin, xac, xim, 0, n0, tid, 1024);
  __syncthreads();

  float cst[4]  = {};   // LSTM cell state (per-lane, fp32, persistent)
  float mreg[4] = {};   // memory state (waves 0..7, fp32, persistent)

  for (int t = 0; t < T_STEPS; ++t) {
    // ---- Phase 1: gate matmuls (waves 0..14); wave 15: out2 of step t-1 ----
    f32x4 gacc[4];
    if (w == 15) {
      if (t > 0) {
        float bv = biasLds[B_OUT2];
        f32x4 oa0 = {bv,bv,bv,bv};
        bf16x8 as[2], bs[2];
        #pragma unroll
        for (int s = 0; s < 2; ++s) { bs[s] = LB(1224 + s); as[s] = LA(OFF_HID,72, rA, s*32+gA*8); }
        #pragma unroll
        for (int s = 0; s < 2; ++s) oa0 = MFMA_B16(as[s], bs[s], oa0);
        if (rA == 0) {
          #pragma unroll
          for (int j = 0; j < 4; ++j)
            __builtin_nontemporal_store(oa0[j], &out[(size_t)(n0 + gA*4 + j)*T_STEPS + (t-1)]);
        }
      }
    } else {
      GT g = gate_task(w);
      #pragma unroll
      for (int q = 0; q < 4; ++q) {
        float bv = biasLds[g.bb + g.blk*64 + q*16 + rA];
        gacc[q] = (f32x4){bv,bv,bv,bv};
      }
      if (w < 6)      gate_reg<10,13>(gacc, lds, packc, lane, rA, gA, g.xoff, g.xst, g.hsec, g.tb, g.kt);
      else if (w < 9) gate_reg<3,5>  (gacc, lds, packc, lane, rA, gA, g.xoff, g.xst, g.hsec, g.tb, g.kt);
      else            gate_reg<2,5>  (gacc, lds, packc, lane, rA, gA, g.xoff, g.xst, g.hsec, g.tb, g.kt);
    }
    __syncthreads();

    // ---- Phase 2: LSTM elementwise; write c_star(prev,new) + feats(h) ----
    if (w < 15) {
      GT g = gate_task(w);
      int unit = g.blk*16 + rA;
      if (unit < g.H) {
        #pragma unroll
        for (int j = 0; j < 4; ++j) {
          float iv = sigm (gacc[0][j]);
          float fv = sigm (gacc[1][j]);
          float gv = tanh_(gacc[2][j]);
          float ov = sigm (gacc[3][j]);
          float cp = cst[j];
          float cn = fv*cp + iv*gv;
          float hn = ov*tanh_(cn);
          cst[j] = cn;
          int row = gA*4 + j;
          STB(OFF_CSTAR,456, row, g.hsec + unit,        cp);
          STB(OFF_CSTAR,456, row, 224 + g.hsec + unit,  cn);
          STB(OFF_FEATS,360, row, g.hsec + unit,        hn);
        }
      }
    }
    __syncthreads();

    // ---- Phase 3: att1 layer1 (c_star -> relu -> att1h) ----
    if (w < 8) {
      int n = w;
      float bv = biasLds[B_A1H + n*16 + rA];
      f32x4 a0v = {bv,bv,bv,bv};
      bf16x8 a = LA(OFF_CSTAR,456, rA, gA*8);
      reg_loop<14>(packc, lane,
        [&](int i){ return 492 + n*14 + i; },
        [&](int i, bf16x8 bv8){
          a0v = MFMA_B16(a, bv8, a0v);
          if (i + 1 < 14) a = LA(OFF_CSTAR,456, rA, (i+1)*32+gA*8);
        });
      #pragma unroll
      for (int j = 0; j < 4; ++j)
        STB(OFF_HID,136, gA*4 + j, n*16 + rA, fmaxf(a0v[j], 0.f));
    }
    __syncthreads();

    // ---- Phase 4: att1 layer2 -> logits (att_buf) ----
    {
      float bv1 = biasLds[B_LOG + w*16 + rA];
      if (w < 12) {
        float bv2 = biasLds[B_LOG + (w+16)*16 + rA];
        f32x4 l0 = {bv1,bv1,bv1,bv1}, l1 = {bv2,bv2,bv2,bv2};
        bf16x8 a = LA(OFF_HID,136, rA, gA*8);
        reg_loop<8>(packc, lane,
          [&](int i){ int tau = (i < 4) ? w : (w + 16); return 604 + tau*4 + (i & 3); },
          [&](int i, bf16x8 bv8){
            if (i < 4) l0 = MFMA_B16(a, bv8, l0); else l1 = MFMA_B16(a, bv8, l1);
            if (i + 1 < 8) a = LA(OFF_HID,136, rA, ((i+1)&3)*32+gA*8);
          });
        #pragma unroll
        for (int j = 0; j < 4; ++j) {
          STB(OFF_ATT,456, gA*4 + j, w*16 + rA,      l0[j]);
          STB(OFF_ATT,456, gA*4 + j, (w+16)*16 + rA, l1[j]);
        }
      } else {
        f32x4 l0 = {bv1,bv1,bv1,bv1};
        bf16x8 a = LA(OFF_HID,136, rA, gA*8);
        reg_loop<4>(packc, lane,
          [&](int i){ return 604 + w*4 + i; },
          [&](int i, bf16x8 bv8){
            l0 = MFMA_B16(a, bv8, l0);
            if (i + 1 < 4) a = LA(OFF_HID,136, rA, (i+1)*32+gA*8);
          });
        #pragma unroll
        for (int j = 0; j < 4; ++j)
          STB(OFF_ATT,456, gA*4 + j, w*16 + rA, l0[j]);
      }
    }
    __syncthreads();

    // ---- Phase 5: softmax(448)*c_star (waves 0..7) ; stage x_{t+1} (8..15) --
    if (w < 8) {
      int row = w*2 + (lane >> 5);
      int cb  = lane & 31;
      float v[14];
      float mx = -3.0e38f;
      #pragma unroll
      for (int q = 0; q < 14; ++q) { v[q] = LDB(OFF_ATT,456,row, cb + 32*q); mx = fmaxf(mx, v[q]); }
      #pragma unroll
      for (int mk = 1; mk < 32; mk <<= 1) mx = fmaxf(mx, __shfl_xor(mx, mk));
      float sm = 0.f;
      #pragma unroll
      for (int q = 0; q < 14; ++q) { v[q] = __expf(v[q] - mx); sm += v[q]; }
      #pragma unroll
      for (int mk = 1; mk < 32; mk <<= 1) sm += __shfl_xor(sm, mk);
      float inv = 1.0f / sm;
      #pragma unroll
      for (int q = 0; q < 14; ++q) {
        int c = cb + 32*q;
        float cs = LDB(OFF_CSTAR,456,row,c);
        STB(OFF_ATT,456,row,c, v[q]*inv*cs);
      }
    } else if (t < T_STEPS-1) {
      stage_x(lds, xlin, xac, xim, t+1, n0, tid - 512, 512);
    }
    __syncthreads();

    // ---- Phase 6: att2 layer1 (waves 8..15, 2 n-tiles); g1/g2 (waves 0..7) --
    if (w >= 8) {
      int nb = (w - 8)*2;
      float b0 = biasLds[B_A2H + nb*16 + rA];
      float b1 = biasLds[B_A2H + (nb+1)*16 + rA];
      f32x4 A0 = {b0,b0,b0,b0}, A1 = {b1,b1,b1,b1};
      bf16x8 a = LA(OFF_ATT,456, rA, gA*8);
      reg_loop<28>(packc, lane,
        [&](int i){ int rr = (i >= 14) ? 1 : 0; int s = i - (rr ? 14 : 0); return 716 + (nb+rr)*14 + s; },
        [&](int i, bf16x8 bv8){
          if (i < 14) A0 = MFMA_B16(a, bv8, A0); else A1 = MFMA_B16(a, bv8, A1);
          if (i + 1 < 28) {
            int ns = (i + 1 < 14) ? (i + 1) : (i + 1 - 14);
            a = LA(OFF_ATT,456, rA, ns*32+gA*8);
          }
        });
      #pragma unroll
      for (int j = 0; j < 4; ++j) {
        STB(OFF_HID,264, gA*4 + j, nb*16 + rA,     fmaxf(A0[j], 0.f));
        STB(OFF_HID,264, gA*4 + j, (nb+1)*16 + rA, fmaxf(A1[j], 0.f));
      }
    } else {
      int which = w >> 2;          // 0: g1, 1: g2
      int n = w & 3;
      int tbq = which ? 1076 : 1004;
      int bb  = which ? B_G2H : B_G1H;
      int oo  = which ? OFF_G2H : OFF_G1H;
      float bv = biasLds[bb + n*16 + rA];
      f32x4 A0 = {bv,bv,bv,bv};
      bf16x8 a = LA(OFF_ATT,456, rA, gA*8);
      reg_loop<18>(packc, lane,
        [&](int i){ return tbq + n*18 + i; },
        [&](int i, bf16x8 bv8){
          A0 = MFMA_B16(a, bv8, A0);
          if (i + 1 < 18) {
            a = (i + 1 < 14) ? LA(OFF_ATT,456, rA, (i+1)*32+gA*8)
                             : LA(OFF_FEATS,360, rA, 224 + (i+1-14)*32 + gA*8);
          }
        });
      #pragma unroll
      for (int j = 0; j < 4; ++j)
        STB(oo,72, gA*4 + j, n*16 + rA, fmaxf(A0[j], 0.f));
    }
    __syncthreads();

    // ---- Phase 7: att2 layer2 (tanh->c_hat) + gammas + mem update ----
    if (w < 8) {
      int n = w;
      float bc = biasLds[B_CHAT + n*16 + rA];
      float b1 = biasLds[B_GM1  + n*16 + rA];
      float b2 = biasLds[B_GM2  + n*16 + rA];
      f32x4 cc0={bc,bc,bc,bc};
      f32x4 g10={b1,b1,b1,b1};
      f32x4 g20={b2,b2,b2,b2};
      bf16x8 a = LA(OFF_HID,264, rA, gA*8);
      reg_loop<12>(packc, lane,
        [&](int i){
          if (i < 8)  return 940 + n*8 + i;
          if (i < 10) return 1148 + n*2 + (i - 8);
          return 1164 + n*2 + (i - 10);
        },
        [&](int i, bf16x8 bv8){
          if (i < 8)       cc0 = MFMA_B16(a, bv8, cc0);
          else if (i < 10) g10 = MFMA_B16(a, bv8, g10);
          else             g20 = MFMA_B16(a, bv8, g20);
          if (i + 1 < 8)        a = LA(OFF_HID,264, rA, (i+1)*32+gA*8);
          else if (i + 1 < 10)  a = LA(OFF_G1H,72, rA, (i+1-8)*32+gA*8);
          else if (i + 1 < 12)  a = LA(OFF_G2H,72, rA, (i+1-10)*32+gA*8);
        });
      #pragma unroll
      for (int j = 0; j < 4; ++j) {
        float ch = tanh_(cc0[j]), ga = sigm(g10[j]), gb = sigm(g20[j]);
        float mn = ga*mreg[j] + gb*ch;
        mreg[j] = mn;
        STB(OFF_FEATS,360, gA*4 + j, 224 + n*16 + rA, mn);
      }
    }
    __syncthreads();

    // ---- Phase 8: out layer1 (feats -> relu -> outh) ----
    if (w < 4) {
      int n = w;
      float bv = biasLds[B_OUTH + n*16 + rA];
      f32x4 a0v = {bv,bv,bv,bv};
      bf16x8 a = LA(OFF_FEATS,360, rA, gA*8);
      reg_loop<11>(packc, lane,
        [&](int i){ return 1180 + n*11 + i; },
        [&](int i, bf16x8 bv8){
          a0v = MFMA_B16(a, bv8, a0v);
          if (i + 1 < 11) a = LA(OFF_FEATS,360, rA, (i+1)*32+gA*8);
        });
      #pragma unroll
      for (int j = 0; j < 4; ++j)
        STB(OFF_HID,72, gA*4 + j, n*16 + rA, fmaxf(a0v[j], 0.f));
    }
    __syncthreads();
  }

  // ---- Final out2 for t = 127 ----
  if (w == 15) {
    float bv = biasLds[B_OUT2];
    f32x4 oa0 = {bv,bv,bv,bv};
    bf16x8 as[2], bs[2];
    #pragma unroll
    for (int s = 0; s < 2; ++s) { bs[s] = LB(1224 + s); as[s] = LA(OFF_HID,72, rA, s*32+gA*8); }
    #pragma unroll
    for (int s = 0; s < 2; ++s) oa0 = MFMA_B16(as[s], bs[s], oa0);
    if (rA == 0) {
      #pragma unroll
      for (int j = 0; j < 4; ++j)
        __builtin_nontemporal_store(oa0[j], &out[(size_t)(n0 + gA*4 + j)*T_STEPS + 127]);
    }
  }
}

extern "C" void kernel_launch(void* const* d_in, const int* in_sizes, int n_in,
                              void* d_out, int out_size, void* d_ws, size_t ws_size,
                              hipStream_t stream) {
  (void)in_sizes; (void)n_in; (void)out_size; (void)ws_size;
  PP P;
  for (int i = 0; i < 35; ++i) P.p[i] = (const float*)d_in[i];
  unsigned short* pack = (unsigned short*)d_ws;
  float* bias = (float*)((char*)d_ws + PACK_BYTES);

  hipLaunchKernelGGL(pack_kernel, dim3(320), dim3(256), 0, stream, P, pack, bias);
  hipLaunchKernelGGL(fused_kernel, dim3(128), dim3(1024), 0, stream,
                     P.p[0], P.p[1], P.p[2], pack, bias, (float*)d_out);
}